// Round 2
// baseline (3400.689 us; speedup 1.0000x reference)
//
#include <hip/hip_runtime.h>
#include <hip/hip_bf16.h>
#include <math.h>

#define BB 32
#define TT 4096
#define DD 256
#define LL 2
#define NC 64          // number of time chunks for the scan
#define CH 64          // chunk length (NC*CH == TT)
#define MM (BB*TT)     // 131072 rows
#define NTILES 512     // MM / 256 rows per tile
#define EPSV 1e-5f

typedef __bf16 bf16;
typedef __attribute__((ext_vector_type(8))) __bf16 bf16x8;
typedef __attribute__((ext_vector_type(4))) __bf16 bf16x4;
typedef __attribute__((ext_vector_type(2))) __bf16 bf16x2;
typedef __attribute__((ext_vector_type(4))) float f32x4;

// ---------------------------------------------------------------------------
__device__ __forceinline__ float decay_of(int d) {
    const float l0 = 2.302585092994046f;      // log(10)
    const float l1 = 7.6009024595420815f;     // log(2000)
    float lt = l0 + (float)d * (l1 - l0) * (1.0f / 255.0f);
    return expf(-expf(-lt));
}
__device__ __forceinline__ float silu_f(float v) { return v / (1.0f + expf(-v)); }

// ---------------------------------------------------------------------------
// one-shot fp32 -> bf16 conversion of all three weight tensors
__global__ void cvtw_k(const float* __restrict__ we, const float* __restrict__ wi,
                       const float* __restrict__ wo, bf16* __restrict__ de,
                       bf16* __restrict__ di, bf16* __restrict__ dk)
{
    int i = blockIdx.x * 1024 + threadIdx.x;            // 458752 total
    if (i < 65536)            de[i] = (bf16)we[i];
    else if (i < 327680)      di[i - 65536] = (bf16)wi[i - 65536];
    else if (i < 458752)      dk[i - 327680] = (bf16)wo[i - 327680];
}

// ---------------------------------------------------------------------------
// GEMM: rows of A (M=131072, K=256) x W(256 cols per blockIdx.y)^T + bias.
// Swapped-operand MFMA: D row = W-col (lane>>4)*4+i, D col = A-row (lane&15).
// Per lane: one A-row, 4 consecutive output cols per frag -> vector epilogues.
// EPI 1: LN+ReLU -> O0 bf16            (encoder)
// EPI 2: O0 += acc (in-place bf16 h)   (out_proj layer 0)
// EPI 3: colblk0 -> O0 plain; colblk1 -> silu -> O1    (in_proj)
// EPI 4: acc += O0(h); rowwise LN; -> Of fp32          (out_proj layer 1 + final LN)
template<int SRCF32, int EPI>
__global__ __launch_bounds__(1024, 4)
void gemm_k(const void* __restrict__ Asrc,
            const bf16* __restrict__ W,
            const float* __restrict__ bias,
            const float* __restrict__ g1, const float* __restrict__ b1,
            bf16* __restrict__ O0, bf16* __restrict__ O1,
            float* __restrict__ Of)
{
    __shared__ char lds[131072];   // 256 cols x 512B (K=256 bf16), XOR-swizzled
    const int tid = threadIdx.x;
    const int colblk = blockIdx.y * 256;
    const bf16* Wblk = W + (size_t)colblk * 256;

    #pragma unroll
    for (int i = 0; i < 8; ++i) {
        int idx = tid + i * 1024;
        int n  = idx >> 5;          // col (0..255)
        int kc = idx & 31;          // 16B chunk within 512B row
        *(bf16x8*)(&lds[n * 512 + ((kc * 16) ^ ((n & 7) << 4))]) =
            *(const bf16x8*)(Wblk + n * 256 + kc * 8);
    }
    __syncthreads();

    const int wave = tid >> 6, lane = tid & 63;
    const int r = lane & 15, g4 = lane >> 4;
    const int c4 = g4 * 4;                       // first of 4 consecutive cols

    for (int tile = blockIdx.x; tile < NTILES; tile += gridDim.x) {
        const size_t row = (size_t)tile * 256 + wave * 16 + r;

        // A fragments: row fixed, k = kk*32 + g4*8 .. +7
        bf16x8 af[8];
        if (SRCF32) {
            const float* ap0 = (const float*)Asrc + row * 256;
            #pragma unroll
            for (int kk = 0; kk < 8; ++kk) {
                const float* ap = ap0 + kk * 32 + g4 * 8;
                float4 f0 = *(const float4*)ap;
                float4 f1 = *(const float4*)(ap + 4);
                bf16x8 t;
                t[0]=(bf16)f0.x; t[1]=(bf16)f0.y; t[2]=(bf16)f0.z; t[3]=(bf16)f0.w;
                t[4]=(bf16)f1.x; t[5]=(bf16)f1.y; t[6]=(bf16)f1.z; t[7]=(bf16)f1.w;
                af[kk] = t;
            }
        } else {
            const bf16* ap0 = (const bf16*)Asrc + row * 256;
            #pragma unroll
            for (int kk = 0; kk < 8; ++kk)
                af[kk] = *(const bf16x8*)(ap0 + kk * 32 + g4 * 8);
        }

        f32x4 acc[16];
        #pragma unroll
        for (int nt = 0; nt < 16; ++nt) {
            float4 bv = *(const float4*)(bias + colblk + nt * 16 + c4);
            acc[nt] = (f32x4){bv.x, bv.y, bv.z, bv.w};
        }

        #pragma unroll
        for (int kk = 0; kk < 8; ++kk) {
            const int kb = kk * 64 + g4 * 16;
            #pragma unroll
            for (int nt = 0; nt < 16; ++nt) {
                int col = nt * 16 + r;
                bf16x8 bfr = *(const bf16x8*)(&lds[col * 512 + (kb ^ ((col & 7) << 4))]);
                acc[nt] = __builtin_amdgcn_mfma_f32_16x16x32_bf16(bfr, af[kk], acc[nt], 0, 0, 0);
            }
        }

        if (EPI == 1) {
            float s = 0.f, q = 0.f;
            #pragma unroll
            for (int nt = 0; nt < 16; ++nt)
                #pragma unroll
                for (int i = 0; i < 4; ++i) { float v = acc[nt][i]; s += v; q += v * v; }
            s += __shfl_xor(s, 16); q += __shfl_xor(q, 16);
            s += __shfl_xor(s, 32); q += __shfl_xor(q, 32);
            float mean = s * (1.0f / 256.0f);
            float rstd = rsqrtf(q * (1.0f / 256.0f) - mean * mean + EPSV);
            #pragma unroll
            for (int nt = 0; nt < 16; ++nt) {
                float4 gg = *(const float4*)(g1 + nt * 16 + c4);
                float4 bb = *(const float4*)(b1 + nt * 16 + c4);
                bf16x4 st;
                st[0] = (bf16)fmaxf((acc[nt][0] - mean) * rstd * gg.x + bb.x, 0.f);
                st[1] = (bf16)fmaxf((acc[nt][1] - mean) * rstd * gg.y + bb.y, 0.f);
                st[2] = (bf16)fmaxf((acc[nt][2] - mean) * rstd * gg.z + bb.z, 0.f);
                st[3] = (bf16)fmaxf((acc[nt][3] - mean) * rstd * gg.w + bb.w, 0.f);
                *(bf16x4*)(O0 + row * 256 + nt * 16 + c4) = st;
            }
        } else if (EPI == 2) {
            #pragma unroll
            for (int nt = 0; nt < 16; ++nt) {
                bf16* p = O0 + row * 256 + nt * 16 + c4;
                bf16x4 hv = *(const bf16x4*)p;
                bf16x4 st;
                #pragma unroll
                for (int i = 0; i < 4; ++i) st[i] = (bf16)(acc[nt][i] + (float)hv[i]);
                *(bf16x4*)p = st;
            }
        } else if (EPI == 3) {
            bf16* dst = blockIdx.y ? O1 : O0;
            const int dosilu = blockIdx.y;
            #pragma unroll
            for (int nt = 0; nt < 16; ++nt) {
                bf16x4 st;
                #pragma unroll
                for (int i = 0; i < 4; ++i) {
                    float v = acc[nt][i];
                    if (dosilu) v = silu_f(v);
                    st[i] = (bf16)v;
                }
                *(bf16x4*)(dst + row * 256 + nt * 16 + c4) = st;
            }
        } else { // EPI == 4
            #pragma unroll
            for (int nt = 0; nt < 16; ++nt) {
                bf16x4 hv = *(const bf16x4*)(O0 + row * 256 + nt * 16 + c4);
                #pragma unroll
                for (int i = 0; i < 4; ++i) acc[nt][i] += (float)hv[i];
            }
            float s = 0.f, q = 0.f;
            #pragma unroll
            for (int nt = 0; nt < 16; ++nt)
                #pragma unroll
                for (int i = 0; i < 4; ++i) { float v = acc[nt][i]; s += v; q += v * v; }
            s += __shfl_xor(s, 16); q += __shfl_xor(q, 16);
            s += __shfl_xor(s, 32); q += __shfl_xor(q, 32);
            float mean = s * (1.0f / 256.0f);
            float rstd = rsqrtf(q * (1.0f / 256.0f) - mean * mean + EPSV);
            #pragma unroll
            for (int nt = 0; nt < 16; ++nt) {
                float4 gg = *(const float4*)(g1 + nt * 16 + c4);
                float4 bb = *(const float4*)(b1 + nt * 16 + c4);
                float4 o;
                o.x = (acc[nt][0] - mean) * rstd * gg.x + bb.x;
                o.y = (acc[nt][1] - mean) * rstd * gg.y + bb.y;
                o.z = (acc[nt][2] - mean) * rstd * gg.z + bb.z;
                o.w = (acc[nt][3] - mean) * rstd * gg.w + bb.w;
                *(float4*)(Of + row * 256 + nt * 16 + c4) = o;
            }
        }
    }
}

// ---------------------------------------------------------------------------
// pass 1: conv(K=4)+SiLU+local EMA inside a 64-step chunk; emit chunk-final only.
// 128 threads, 2 channels per thread (bf16x2 loads).
__global__ void pass1_k(const bf16* __restrict__ xc,
                        const float* __restrict__ cw, const float* __restrict__ cb,
                        float* __restrict__ cfin)
{
    const int d0 = threadIdx.x * 2;
    const int c = blockIdx.x, b = blockIdx.y;
    const int t0 = c * CH;
    const float w00=cw[d0*4+0], w01=cw[d0*4+1], w02=cw[d0*4+2], w03=cw[d0*4+3];
    const float w10=cw[d0*4+4], w11=cw[d0*4+5], w12=cw[d0*4+6], w13=cw[d0*4+7];
    const float bb0 = cb[d0], bb1 = cb[d0+1];
    const float a0 = decay_of(d0), a1 = decay_of(d0+1);
    const size_t base = (size_t)b * TT * 256 + d0;
    float x0m1=0,x0m2=0,x0m3=0, x1m1=0,x1m2=0,x1m3=0;
    if (t0 >= 1) { bf16x2 p = *(const bf16x2*)(xc + base + (size_t)(t0-1)*256); x0m1=(float)p[0]; x1m1=(float)p[1]; }
    if (t0 >= 2) { bf16x2 p = *(const bf16x2*)(xc + base + (size_t)(t0-2)*256); x0m2=(float)p[0]; x1m2=(float)p[1]; }
    if (t0 >= 3) { bf16x2 p = *(const bf16x2*)(xc + base + (size_t)(t0-3)*256); x0m3=(float)p[0]; x1m3=(float)p[1]; }
    float h0 = 0.f, h1 = 0.f;
    for (int t = t0; t < t0 + CH; ++t) {
        bf16x2 p = *(const bf16x2*)(xc + base + (size_t)t * 256);
        float xa = (float)p[0], xb = (float)p[1];
        float v0 = w03*xa + w02*x0m1 + w01*x0m2 + w00*x0m3 + bb0;
        float v1 = w13*xb + w12*x1m1 + w11*x1m2 + w10*x1m3 + bb1;
        h0 = a0*h0 + (1.f-a0)*silu_f(v0);
        h1 = a1*h1 + (1.f-a1)*silu_f(v1);
        x0m3=x0m2; x0m2=x0m1; x0m1=xa;
        x1m3=x1m2; x1m2=x1m1; x1m1=xb;
    }
    *(float2*)(cfin + ((size_t)b*NC + c)*256 + d0) = make_float2(h0, h1);
}

// pass 2: per-(b,d) carry recurrence over the 64 chunk finals.
__global__ void scan2_k(const float* __restrict__ cfin, float* __restrict__ cin)
{
    const int d = threadIdx.x, b = blockIdx.x;
    float a = decay_of(d);
    float aC = a;
    #pragma unroll
    for (int j = 0; j < 6; ++j) aC *= aC;   // a^64
    float H = 0.f;
    for (int c = 0; c < NC; ++c) {
        size_t o = ((size_t)b * NC + c) * 256 + d;
        cin[o] = H;
        H = aC * H + cfin[o];
    }
}

// pass 3: recompute conv+SiLU+EMA with exact carry-in; u = hi * sz; u aliases sz.
__global__ void pass3_k(const bf16* __restrict__ xc, const float* __restrict__ cin,
                        const float* __restrict__ cw, const float* __restrict__ cb,
                        bf16* __restrict__ szu)
{
    const int d0 = threadIdx.x * 2;
    const int c = blockIdx.x, b = blockIdx.y;
    const int t0 = c * CH;
    const float w00=cw[d0*4+0], w01=cw[d0*4+1], w02=cw[d0*4+2], w03=cw[d0*4+3];
    const float w10=cw[d0*4+4], w11=cw[d0*4+5], w12=cw[d0*4+6], w13=cw[d0*4+7];
    const float bb0 = cb[d0], bb1 = cb[d0+1];
    const float a0 = decay_of(d0), a1 = decay_of(d0+1);
    const size_t base = (size_t)b * TT * 256 + d0;
    float2 Hc = *(const float2*)(cin + ((size_t)b*NC + c)*256 + d0);
    float h0 = Hc.x, h1 = Hc.y;
    float x0m1=0,x0m2=0,x0m3=0, x1m1=0,x1m2=0,x1m3=0;
    if (t0 >= 1) { bf16x2 p = *(const bf16x2*)(xc + base + (size_t)(t0-1)*256); x0m1=(float)p[0]; x1m1=(float)p[1]; }
    if (t0 >= 2) { bf16x2 p = *(const bf16x2*)(xc + base + (size_t)(t0-2)*256); x0m2=(float)p[0]; x1m2=(float)p[1]; }
    if (t0 >= 3) { bf16x2 p = *(const bf16x2*)(xc + base + (size_t)(t0-3)*256); x0m3=(float)p[0]; x1m3=(float)p[1]; }
    for (int t = t0; t < t0 + CH; ++t) {
        bf16x2 p = *(const bf16x2*)(xc + base + (size_t)t * 256);
        float xa = (float)p[0], xb = (float)p[1];
        float v0 = w03*xa + w02*x0m1 + w01*x0m2 + w00*x0m3 + bb0;
        float v1 = w13*xb + w12*x1m1 + w11*x1m2 + w10*x1m3 + bb1;
        h0 = a0*h0 + (1.f-a0)*silu_f(v0);
        h1 = a1*h1 + (1.f-a1)*silu_f(v1);
        x0m3=x0m2; x0m2=x0m1; x0m1=xa;
        x1m3=x1m2; x1m2=x1m1; x1m1=xb;
        bf16* up = szu + base + (size_t)t * 256;
        bf16x2 sp = *(const bf16x2*)up;
        bf16x2 st;
        st[0] = (bf16)(h0 * (float)sp[0]);
        st[1] = (bf16)(h1 * (float)sp[1]);
        *(bf16x2*)up = st;
    }
}

// ---------------------------------------------------------------------------
extern "C" void kernel_launch(void* const* d_in, const int* in_sizes, int n_in,
                              void* d_out, int out_size, void* d_ws, size_t ws_size,
                              hipStream_t stream)
{
    (void)in_sizes; (void)n_in; (void)out_size;
    const float* x        = (const float*)d_in[0];
    const float* enc_w    = (const float*)d_in[1];
    const float* enc_b    = (const float*)d_in[2];
    const float* enc_ln_g = (const float*)d_in[3];
    const float* enc_ln_b = (const float*)d_in[4];
    const float* in_proj_w  = (const float*)d_in[5];
    const float* in_proj_b  = (const float*)d_in[6];
    const float* conv_w     = (const float*)d_in[7];
    const float* conv_b     = (const float*)d_in[8];
    const float* out_proj_w = (const float*)d_in[9];
    const float* out_proj_b = (const float*)d_in[10];
    const float* lnf_g      = (const float*)d_in[11];
    const float* lnf_b      = (const float*)d_in[12];

    // workspace: h (64MiB) | sz/u (64MiB) | wenc 128K | winp 512K | woutp 256K | cfin 2M | cin 2M
    if (ws_size < 139329536u) return;
    char* ws = (char*)d_ws;
    bf16*  h     = (bf16*)(ws);
    bf16*  szu   = (bf16*)(ws + 67108864);
    bf16*  wenc  = (bf16*)(ws + 134217728);
    bf16*  winp  = (bf16*)(ws + 134217728 + 131072);
    bf16*  woutp = (bf16*)(ws + 134217728 + 131072 + 524288);
    float* cfin  = (float*)(ws + 134217728 + 917504);
    float* cin   = (float*)(ws + 134217728 + 917504 + 2097152);
    bf16*  xc    = (bf16*)d_out;   // first 64 MiB of d_out as bf16 scratch

    cvtw_k<<<dim3(448), dim3(1024), 0, stream>>>(enc_w, in_proj_w, out_proj_w,
                                                 wenc, winp, woutp);

    dim3 gblk(1024);
    // encoder: h = relu(LN(x @ enc_w^T + enc_b))
    gemm_k<1, 1><<<dim3(256, 1), gblk, 0, stream>>>(x, wenc, enc_b,
                                                    enc_ln_g, enc_ln_b, h, nullptr, nullptr);
    for (int l = 0; l < LL; ++l) {
        // xc = h @ Wx^T + bx ; sz = silu(h @ Wz^T + bz)
        gemm_k<0, 3><<<dim3(256, 2), gblk, 0, stream>>>(h, winp + (size_t)l * 512 * 256,
                                                        in_proj_b + l * 512, nullptr, nullptr,
                                                        xc, szu, nullptr);
        pass1_k<<<dim3(NC, BB), dim3(128), 0, stream>>>(xc, conv_w + l * DD * 4,
                                                        conv_b + l * DD, cfin);
        scan2_k<<<dim3(BB), dim3(256), 0, stream>>>(cfin, cin);
        pass3_k<<<dim3(NC, BB), dim3(128), 0, stream>>>(xc, cin, conv_w + l * DD * 4,
                                                        conv_b + l * DD, szu);
        if (l == 0) {
            // h += u @ out_proj_w[0]^T + b
            gemm_k<0, 2><<<dim3(256, 1), gblk, 0, stream>>>(szu, woutp,
                                                            out_proj_b, nullptr, nullptr,
                                                            h, nullptr, nullptr);
        } else {
            // out = LN(h + u @ out_proj_w[1]^T + b)  -> fp32 d_out
            gemm_k<0, 4><<<dim3(256, 1), gblk, 0, stream>>>(szu, woutp + (size_t)256 * 256,
                                                            out_proj_b + 256, lnf_g, lnf_b,
                                                            h, nullptr, (float*)d_out);
        }
    }
}

// Round 3
// 2660.253 us; speedup vs baseline: 1.2783x; 1.2783x over previous
//
#include <hip/hip_runtime.h>
#include <hip/hip_bf16.h>
#include <math.h>

#define BB 32
#define TT 4096
#define DD 256
#define LL 2
#define NC 64          // number of time chunks for the scan
#define CH 64          // chunk length (NC*CH == TT)
#define MM (BB*TT)     // 131072 rows
#define NTILES 1024    // MM / 128 rows per tile
#define GRIDX 256      // blocks in x; each block loops NTILES/GRIDX = 4 tiles
#define EPSV 1e-5f

typedef __bf16 bf16;
typedef __attribute__((ext_vector_type(8))) __bf16 bf16x8;
typedef __attribute__((ext_vector_type(4))) __bf16 bf16x4;
typedef __attribute__((ext_vector_type(2))) __bf16 bf16x2;
typedef __attribute__((ext_vector_type(4))) float f32x4;

// ---------------------------------------------------------------------------
__device__ __forceinline__ float decay_of(int d) {
    const float l0 = 2.302585092994046f;      // log(10)
    const float l1 = 7.6009024595420815f;     // log(2000)
    float lt = l0 + (float)d * (l1 - l0) * (1.0f / 255.0f);
    return expf(-expf(-lt));
}
__device__ __forceinline__ float silu_f(float v) { return v / (1.0f + expf(-v)); }

// ---------------------------------------------------------------------------
// one-shot fp32 -> bf16 conversion of all three weight tensors
__global__ void cvtw_k(const float* __restrict__ we, const float* __restrict__ wi,
                       const float* __restrict__ wo, bf16* __restrict__ de,
                       bf16* __restrict__ di, bf16* __restrict__ dk)
{
    int i = blockIdx.x * 1024 + threadIdx.x;            // 458752 total
    if (i < 65536)            de[i] = (bf16)we[i];
    else if (i < 327680)      di[i - 65536] = (bf16)wi[i - 65536];
    else if (i < 458752)      dk[i - 327680] = (bf16)wo[i - 327680];
}

// ---------------------------------------------------------------------------
// GEMM: rows of A (M=131072, K=256) x W(256 cols per blockIdx.y)^T + bias.
// Swapped-operand MFMA: D row = W-col (lane>>4)*4+i, D col = A-row (lane&15).
// 512 threads / 8 waves, each wave owns 16 A-rows; block tile = 128 rows.
// Each block loops 4 tiles with W staged in LDS once; A-frags double-buffered.
// EPI 1: LN+ReLU -> O0 bf16            (encoder)
// EPI 2: O0 += acc (in-place bf16 h)   (out_proj layer 0)
// EPI 3: colblk0 -> O0 plain; colblk1 -> silu -> O1    (in_proj)
// EPI 4: acc += O0(h); rowwise LN; -> Of fp32          (out_proj layer 1 + final LN)
template<int SRCF32, int EPI>
__global__ __launch_bounds__(512, 1)
void gemm_k(const void* __restrict__ Asrc,
            const bf16* __restrict__ W,
            const float* __restrict__ bias,
            const float* __restrict__ g1, const float* __restrict__ b1,
            bf16* __restrict__ O0, bf16* __restrict__ O1,
            float* __restrict__ Of)
{
    __shared__ char lds[131072];   // 256 cols x 512B (K=256 bf16), XOR-swizzled
    const int tid = threadIdx.x;
    const int colblk = blockIdx.y * 256;
    const bf16* Wblk = W + (size_t)colblk * 256;

    #pragma unroll
    for (int i = 0; i < 16; ++i) {
        int idx = tid + i * 512;
        int n  = idx >> 5;          // col (0..255)
        int kc = idx & 31;          // 16B chunk within 512B row
        *(bf16x8*)(&lds[n * 512 + ((kc * 16) ^ ((n & 7) << 4))]) =
            *(const bf16x8*)(Wblk + n * 256 + kc * 8);
    }
    __syncthreads();

    const int wave = tid >> 6, lane = tid & 63;
    const int r = lane & 15, g4 = lane >> 4;
    const int c4 = g4 * 4;                       // first of 4 consecutive cols

    auto load_af = [&](int tile, bf16x8 af[8]) {
        const size_t row = (size_t)tile * 128 + wave * 16 + r;
        if (SRCF32) {
            const float* ap0 = (const float*)Asrc + row * 256;
            #pragma unroll
            for (int kk = 0; kk < 8; ++kk) {
                const float* ap = ap0 + kk * 32 + g4 * 8;
                float4 f0 = *(const float4*)ap;
                float4 f1 = *(const float4*)(ap + 4);
                bf16x8 t;
                t[0]=(bf16)f0.x; t[1]=(bf16)f0.y; t[2]=(bf16)f0.z; t[3]=(bf16)f0.w;
                t[4]=(bf16)f1.x; t[5]=(bf16)f1.y; t[6]=(bf16)f1.z; t[7]=(bf16)f1.w;
                af[kk] = t;
            }
        } else {
            const bf16* ap0 = (const bf16*)Asrc + row * 256;
            #pragma unroll
            for (int kk = 0; kk < 8; ++kk)
                af[kk] = *(const bf16x8*)(ap0 + kk * 32 + g4 * 8);
        }
    };

    bf16x8 af[8], afn[8];
    load_af(blockIdx.x, af);

    #pragma unroll 1
    for (int j = 0; j < NTILES / GRIDX; ++j) {
        const int tile = blockIdx.x + j * GRIDX;
        if (j < NTILES / GRIDX - 1) load_af(tile + GRIDX, afn);   // prefetch next

        f32x4 acc[16];
        #pragma unroll
        for (int nt = 0; nt < 16; ++nt) {
            float4 bv = *(const float4*)(bias + colblk + nt * 16 + c4);
            acc[nt] = (f32x4){bv.x, bv.y, bv.z, bv.w};
        }

        #pragma unroll
        for (int kk = 0; kk < 8; ++kk) {
            const int kb = kk * 64 + g4 * 16;
            #pragma unroll
            for (int nt = 0; nt < 16; ++nt) {
                int col = nt * 16 + r;
                bf16x8 bfr = *(const bf16x8*)(&lds[col * 512 + (kb ^ ((col & 7) << 4))]);
                acc[nt] = __builtin_amdgcn_mfma_f32_16x16x32_bf16(bfr, af[kk], acc[nt], 0, 0, 0);
            }
        }

        const size_t row = (size_t)tile * 128 + wave * 16 + r;

        if (EPI == 1) {
            float s = 0.f, q = 0.f;
            #pragma unroll
            for (int nt = 0; nt < 16; ++nt)
                #pragma unroll
                for (int i = 0; i < 4; ++i) { float v = acc[nt][i]; s += v; q += v * v; }
            s += __shfl_xor(s, 16); q += __shfl_xor(q, 16);
            s += __shfl_xor(s, 32); q += __shfl_xor(q, 32);
            float mean = s * (1.0f / 256.0f);
            float rstd = rsqrtf(q * (1.0f / 256.0f) - mean * mean + EPSV);
            #pragma unroll
            for (int nt = 0; nt < 16; ++nt) {
                float4 gg = *(const float4*)(g1 + nt * 16 + c4);
                float4 bb = *(const float4*)(b1 + nt * 16 + c4);
                bf16x4 st;
                st[0] = (bf16)fmaxf((acc[nt][0] - mean) * rstd * gg.x + bb.x, 0.f);
                st[1] = (bf16)fmaxf((acc[nt][1] - mean) * rstd * gg.y + bb.y, 0.f);
                st[2] = (bf16)fmaxf((acc[nt][2] - mean) * rstd * gg.z + bb.z, 0.f);
                st[3] = (bf16)fmaxf((acc[nt][3] - mean) * rstd * gg.w + bb.w, 0.f);
                *(bf16x4*)(O0 + row * 256 + nt * 16 + c4) = st;
            }
        } else if (EPI == 2) {
            #pragma unroll
            for (int nt = 0; nt < 16; ++nt) {
                bf16* p = O0 + row * 256 + nt * 16 + c4;
                bf16x4 hv = *(const bf16x4*)p;
                bf16x4 st;
                #pragma unroll
                for (int i = 0; i < 4; ++i) st[i] = (bf16)(acc[nt][i] + (float)hv[i]);
                *(bf16x4*)p = st;
            }
        } else if (EPI == 3) {
            bf16* dst = blockIdx.y ? O1 : O0;
            const int dosilu = blockIdx.y;
            #pragma unroll
            for (int nt = 0; nt < 16; ++nt) {
                bf16x4 st;
                #pragma unroll
                for (int i = 0; i < 4; ++i) {
                    float v = acc[nt][i];
                    if (dosilu) v = silu_f(v);
                    st[i] = (bf16)v;
                }
                *(bf16x4*)(dst + row * 256 + nt * 16 + c4) = st;
            }
        } else { // EPI == 4
            #pragma unroll
            for (int nt = 0; nt < 16; ++nt) {
                bf16x4 hv = *(const bf16x4*)(O0 + row * 256 + nt * 16 + c4);
                #pragma unroll
                for (int i = 0; i < 4; ++i) acc[nt][i] += (float)hv[i];
            }
            float s = 0.f, q = 0.f;
            #pragma unroll
            for (int nt = 0; nt < 16; ++nt)
                #pragma unroll
                for (int i = 0; i < 4; ++i) { float v = acc[nt][i]; s += v; q += v * v; }
            s += __shfl_xor(s, 16); q += __shfl_xor(q, 16);
            s += __shfl_xor(s, 32); q += __shfl_xor(q, 32);
            float mean = s * (1.0f / 256.0f);
            float rstd = rsqrtf(q * (1.0f / 256.0f) - mean * mean + EPSV);
            #pragma unroll
            for (int nt = 0; nt < 16; ++nt) {
                float4 gg = *(const float4*)(g1 + nt * 16 + c4);
                float4 bb = *(const float4*)(b1 + nt * 16 + c4);
                float4 o;
                o.x = (acc[nt][0] - mean) * rstd * gg.x + bb.x;
                o.y = (acc[nt][1] - mean) * rstd * gg.y + bb.y;
                o.z = (acc[nt][2] - mean) * rstd * gg.z + bb.z;
                o.w = (acc[nt][3] - mean) * rstd * gg.w + bb.w;
                *(float4*)(Of + row * 256 + nt * 16 + c4) = o;
            }
        }

        if (j < NTILES / GRIDX - 1) {
            #pragma unroll
            for (int i2 = 0; i2 < 8; ++i2) af[i2] = afn[i2];
        }
    }
}

// ---------------------------------------------------------------------------
// pass 1: conv(K=4)+SiLU+local EMA inside a 64-step chunk; emit chunk-final only.
// 128 threads, 2 channels per thread (bf16x2 loads).
__global__ void pass1_k(const bf16* __restrict__ xc,
                        const float* __restrict__ cw, const float* __restrict__ cb,
                        float* __restrict__ cfin)
{
    const int d0 = threadIdx.x * 2;
    const int c = blockIdx.x, b = blockIdx.y;
    const int t0 = c * CH;
    const float w00=cw[d0*4+0], w01=cw[d0*4+1], w02=cw[d0*4+2], w03=cw[d0*4+3];
    const float w10=cw[d0*4+4], w11=cw[d0*4+5], w12=cw[d0*4+6], w13=cw[d0*4+7];
    const float bb0 = cb[d0], bb1 = cb[d0+1];
    const float a0 = decay_of(d0), a1 = decay_of(d0+1);
    const size_t base = (size_t)b * TT * 256 + d0;
    float x0m1=0,x0m2=0,x0m3=0, x1m1=0,x1m2=0,x1m3=0;
    if (t0 >= 1) { bf16x2 p = *(const bf16x2*)(xc + base + (size_t)(t0-1)*256); x0m1=(float)p[0]; x1m1=(float)p[1]; }
    if (t0 >= 2) { bf16x2 p = *(const bf16x2*)(xc + base + (size_t)(t0-2)*256); x0m2=(float)p[0]; x1m2=(float)p[1]; }
    if (t0 >= 3) { bf16x2 p = *(const bf16x2*)(xc + base + (size_t)(t0-3)*256); x0m3=(float)p[0]; x1m3=(float)p[1]; }
    float h0 = 0.f, h1 = 0.f;
    for (int t = t0; t < t0 + CH; ++t) {
        bf16x2 p = *(const bf16x2*)(xc + base + (size_t)t * 256);
        float xa = (float)p[0], xb = (float)p[1];
        float v0 = w03*xa + w02*x0m1 + w01*x0m2 + w00*x0m3 + bb0;
        float v1 = w13*xb + w12*x1m1 + w11*x1m2 + w10*x1m3 + bb1;
        h0 = a0*h0 + (1.f-a0)*silu_f(v0);
        h1 = a1*h1 + (1.f-a1)*silu_f(v1);
        x0m3=x0m2; x0m2=x0m1; x0m1=xa;
        x1m3=x1m2; x1m2=x1m1; x1m1=xb;
    }
    *(float2*)(cfin + ((size_t)b*NC + c)*256 + d0) = make_float2(h0, h1);
}

// pass 2: per-(b,d) carry recurrence over the 64 chunk finals.
__global__ void scan2_k(const float* __restrict__ cfin, float* __restrict__ cin)
{
    const int d = threadIdx.x, b = blockIdx.x;
    float a = decay_of(d);
    float aC = a;
    #pragma unroll
    for (int j = 0; j < 6; ++j) aC *= aC;   // a^64
    float H = 0.f;
    for (int c = 0; c < NC; ++c) {
        size_t o = ((size_t)b * NC + c) * 256 + d;
        cin[o] = H;
        H = aC * H + cfin[o];
    }
}

// pass 3: recompute conv+SiLU+EMA with exact carry-in; u = hi * sz; u aliases sz.
__global__ void pass3_k(const bf16* __restrict__ xc, const float* __restrict__ cin,
                        const float* __restrict__ cw, const float* __restrict__ cb,
                        bf16* __restrict__ szu)
{
    const int d0 = threadIdx.x * 2;
    const int c = blockIdx.x, b = blockIdx.y;
    const int t0 = c * CH;
    const float w00=cw[d0*4+0], w01=cw[d0*4+1], w02=cw[d0*4+2], w03=cw[d0*4+3];
    const float w10=cw[d0*4+4], w11=cw[d0*4+5], w12=cw[d0*4+6], w13=cw[d0*4+7];
    const float bb0 = cb[d0], bb1 = cb[d0+1];
    const float a0 = decay_of(d0), a1 = decay_of(d0+1);
    const size_t base = (size_t)b * TT * 256 + d0;
    float2 Hc = *(const float2*)(cin + ((size_t)b*NC + c)*256 + d0);
    float h0 = Hc.x, h1 = Hc.y;
    float x0m1=0,x0m2=0,x0m3=0, x1m1=0,x1m2=0,x1m3=0;
    if (t0 >= 1) { bf16x2 p = *(const bf16x2*)(xc + base + (size_t)(t0-1)*256); x0m1=(float)p[0]; x1m1=(float)p[1]; }
    if (t0 >= 2) { bf16x2 p = *(const bf16x2*)(xc + base + (size_t)(t0-2)*256); x0m2=(float)p[0]; x1m2=(float)p[1]; }
    if (t0 >= 3) { bf16x2 p = *(const bf16x2*)(xc + base + (size_t)(t0-3)*256); x0m3=(float)p[0]; x1m3=(float)p[1]; }
    for (int t = t0; t < t0 + CH; ++t) {
        bf16x2 p = *(const bf16x2*)(xc + base + (size_t)t * 256);
        float xa = (float)p[0], xb = (float)p[1];
        float v0 = w03*xa + w02*x0m1 + w01*x0m2 + w00*x0m3 + bb0;
        float v1 = w13*xb + w12*x1m1 + w11*x1m2 + w10*x1m3 + bb1;
        h0 = a0*h0 + (1.f-a0)*silu_f(v0);
        h1 = a1*h1 + (1.f-a1)*silu_f(v1);
        x0m3=x0m2; x0m2=x0m1; x0m1=xa;
        x1m3=x1m2; x1m2=x1m1; x1m1=xb;
        bf16* up = szu + base + (size_t)t * 256;
        bf16x2 sp = *(const bf16x2*)up;
        bf16x2 st;
        st[0] = (bf16)(h0 * (float)sp[0]);
        st[1] = (bf16)(h1 * (float)sp[1]);
        *(bf16x2*)up = st;
    }
}

// ---------------------------------------------------------------------------
extern "C" void kernel_launch(void* const* d_in, const int* in_sizes, int n_in,
                              void* d_out, int out_size, void* d_ws, size_t ws_size,
                              hipStream_t stream)
{
    (void)in_sizes; (void)n_in; (void)out_size;
    const float* x        = (const float*)d_in[0];
    const float* enc_w    = (const float*)d_in[1];
    const float* enc_b    = (const float*)d_in[2];
    const float* enc_ln_g = (const float*)d_in[3];
    const float* enc_ln_b = (const float*)d_in[4];
    const float* in_proj_w  = (const float*)d_in[5];
    const float* in_proj_b  = (const float*)d_in[6];
    const float* conv_w     = (const float*)d_in[7];
    const float* conv_b     = (const float*)d_in[8];
    const float* out_proj_w = (const float*)d_in[9];
    const float* out_proj_b = (const float*)d_in[10];
    const float* lnf_g      = (const float*)d_in[11];
    const float* lnf_b      = (const float*)d_in[12];

    // workspace: h (64MiB) | sz/u (64MiB) | wenc 128K | winp 512K | woutp 256K | cfin 2M | cin 2M
    if (ws_size < 139329536u) return;
    char* ws = (char*)d_ws;
    bf16*  h     = (bf16*)(ws);
    bf16*  szu   = (bf16*)(ws + 67108864);
    bf16*  wenc  = (bf16*)(ws + 134217728);
    bf16*  winp  = (bf16*)(ws + 134217728 + 131072);
    bf16*  woutp = (bf16*)(ws + 134217728 + 131072 + 524288);
    float* cfin  = (float*)(ws + 134217728 + 917504);
    float* cin   = (float*)(ws + 134217728 + 917504 + 2097152);
    bf16*  xc    = (bf16*)d_out;   // first 64 MiB of d_out as bf16 scratch

    cvtw_k<<<dim3(448), dim3(1024), 0, stream>>>(enc_w, in_proj_w, out_proj_w,
                                                 wenc, winp, woutp);

    dim3 gblk(512);
    // encoder: h = relu(LN(x @ enc_w^T + enc_b))
    gemm_k<1, 1><<<dim3(GRIDX, 1), gblk, 0, stream>>>(x, wenc, enc_b,
                                                      enc_ln_g, enc_ln_b, h, nullptr, nullptr);
    for (int l = 0; l < LL; ++l) {
        // xc = h @ Wx^T + bx ; sz = silu(h @ Wz^T + bz)
        gemm_k<0, 3><<<dim3(GRIDX, 2), gblk, 0, stream>>>(h, winp + (size_t)l * 512 * 256,
                                                          in_proj_b + l * 512, nullptr, nullptr,
                                                          xc, szu, nullptr);
        pass1_k<<<dim3(NC, BB), dim3(128), 0, stream>>>(xc, conv_w + l * DD * 4,
                                                        conv_b + l * DD, cfin);
        scan2_k<<<dim3(BB), dim3(256), 0, stream>>>(cfin, cin);
        pass3_k<<<dim3(NC, BB), dim3(128), 0, stream>>>(xc, cin, conv_w + l * DD * 4,
                                                        conv_b + l * DD, szu);
        if (l == 0) {
            // h += u @ out_proj_w[0]^T + b
            gemm_k<0, 2><<<dim3(GRIDX, 1), gblk, 0, stream>>>(szu, woutp,
                                                              out_proj_b, nullptr, nullptr,
                                                              h, nullptr, nullptr);
        } else {
            // out = LN(h + u @ out_proj_w[1]^T + b)  -> fp32 d_out
            gemm_k<0, 4><<<dim3(GRIDX, 1), gblk, 0, stream>>>(szu, woutp + (size_t)256 * 256,
                                                              out_proj_b + 256, lnf_g, lnf_b,
                                                              h, nullptr, (float*)d_out);
        }
    }
}

// Round 4
// 540.578 us; speedup vs baseline: 6.2908x; 4.9211x over previous
//
#include <hip/hip_runtime.h>
#include <hip/hip_bf16.h>
#include <math.h>

#define BB 32
#define TT 4096
#define DD 256
#define LL 2
#define NC 64          // number of time chunks for the scan
#define CH 64          // chunk length (NC*CH == TT)
#define MM (BB*TT)     // 131072 rows
#define EPSV 1e-5f

typedef __bf16 bf16;
typedef __attribute__((ext_vector_type(8))) __bf16 bf16x8;
typedef __attribute__((ext_vector_type(4))) __bf16 bf16x4;
typedef __attribute__((ext_vector_type(2))) __bf16 bf16x2;
typedef __attribute__((ext_vector_type(4))) float f32x4;

// ---------------------------------------------------------------------------
__device__ __forceinline__ float decay_of(int d) {
    const float l0 = 2.302585092994046f;      // log(10)
    const float l1 = 7.6009024595420815f;     // log(2000)
    float lt = l0 + (float)d * (l1 - l0) * (1.0f / 255.0f);
    return expf(-expf(-lt));
}
__device__ __forceinline__ float silu_f(float v) { return v / (1.0f + expf(-v)); }

// ---------------------------------------------------------------------------
// one-shot fp32 -> bf16 conversion of all three weight tensors
__global__ void cvtw_k(const float* __restrict__ we, const float* __restrict__ wi,
                       const float* __restrict__ wo, bf16* __restrict__ de,
                       bf16* __restrict__ di, bf16* __restrict__ dk)
{
    int i = blockIdx.x * 1024 + threadIdx.x;            // 458752 total
    if (i < 65536)            de[i] = (bf16)we[i];
    else if (i < 327680)      di[i - 65536] = (bf16)wi[i - 65536];
    else if (i < 458752)      dk[i - 327680] = (bf16)wo[i - 327680];
}

// ---------------------------------------------------------------------------
// GEMM: C[128 rows x NCOLS cols] = A[M x 256] * W[N x 256]^T + bias, one tile/block.
// Swapped-operand MFMA: D "row" = W-col (lane>>4)*4+i, D "col" = A-row (lane&15).
// 512 threads / 8 waves, wave owns 16 A-rows x NCOLS cols.
// W staged in LDS fragment-major: 16B unit idx = kc*NCOLS + (n ^ (kc&15));
// read banks = ((r^c)&7)*4 -> 32 banks @ 2 lanes each = conflict-free.
// A-fragment global loads issued BEFORE staging so latency hides under it.
// EPI 1: rowwise LN+ReLU -> O0 bf16     (encoder; NCOLS=256 required)
// EPI 2: O0 += acc (in-place bf16 h)
// EPI 3: cols <256 -> O0 plain; cols >=256 -> silu -> O1   (in_proj)
// EPI 4: acc += O0(h); rowwise LN -> Of fp32   (out_proj l1 + final LN; NCOLS=256)
template<int SRCF32, int EPI, int NCOLS, int MINW>
__global__ __launch_bounds__(512, MINW)
void gemm_k(const void* __restrict__ Asrc,
            const bf16* __restrict__ W,
            const float* __restrict__ bias,
            const float* __restrict__ g1, const float* __restrict__ b1,
            bf16* __restrict__ O0, bf16* __restrict__ O1,
            float* __restrict__ Of)
{
    constexpr int NT = NCOLS / 16;                  // mfma col-tiles
    __shared__ bf16x8 ldsW[32 * NCOLS];             // fragment-major, swizzled
    const int tid = threadIdx.x;
    const int colblk = blockIdx.y * NCOLS;
    const bf16* Wblk = W + (size_t)colblk * 256;

    const int wave = tid >> 6, lane = tid & 63;
    const int r = lane & 15, g4 = lane >> 4;
    const int c4 = g4 * 4;                          // first of 4 consecutive cols
    const size_t row = (size_t)blockIdx.x * 128 + wave * 16 + r;

    // ---- issue A-fragment loads first (latency hides under W staging) ----
    bf16x8 af[8];
    if (SRCF32) {
        const float* ap0 = (const float*)Asrc + row * 256;
        #pragma unroll
        for (int kk = 0; kk < 8; ++kk) {
            const float* ap = ap0 + kk * 32 + g4 * 8;
            float4 f0 = *(const float4*)ap;
            float4 f1 = *(const float4*)(ap + 4);
            bf16x8 t;
            t[0]=(bf16)f0.x; t[1]=(bf16)f0.y; t[2]=(bf16)f0.z; t[3]=(bf16)f0.w;
            t[4]=(bf16)f1.x; t[5]=(bf16)f1.y; t[6]=(bf16)f1.z; t[7]=(bf16)f1.w;
            af[kk] = t;
        }
    } else {
        const bf16* ap0 = (const bf16*)Asrc + row * 256;
        #pragma unroll
        for (int kk = 0; kk < 8; ++kk)
            af[kk] = *(const bf16x8*)(ap0 + kk * 32 + g4 * 8);
    }

    // ---- stage W tile (coalesced global reads, swizzled frag-major LDS) ----
    #pragma unroll
    for (int i = 0; i < NT; ++i) {
        int idx = tid + i * 512;        // 0 .. 32*NCOLS
        int n  = idx >> 5;              // W-col within tile
        int kc = idx & 31;              // 16B k-chunk (k = kc*8)
        ldsW[kc * NCOLS + (n ^ (kc & 15))] = *(const bf16x8*)(Wblk + n * 256 + kc * 8);
    }
    __syncthreads();

    f32x4 acc[NT];
    #pragma unroll
    for (int nt = 0; nt < NT; ++nt) {
        float4 bv = *(const float4*)(bias + colblk + nt * 16 + c4);
        acc[nt] = (f32x4){bv.x, bv.y, bv.z, bv.w};
    }

    #pragma unroll
    for (int kk = 0; kk < 8; ++kk) {
        const int kc = kk * 4 + g4;
        const int base = kc * NCOLS;
        const int swz = kc & 15;
        #pragma unroll
        for (int nt = 0; nt < NT; ++nt) {
            bf16x8 bfr = ldsW[base + ((nt * 16 + r) ^ swz)];
            acc[nt] = __builtin_amdgcn_mfma_f32_16x16x32_bf16(bfr, af[kk], acc[nt], 0, 0, 0);
        }
    }

    if (EPI == 1) {                       // LN + ReLU (NCOLS == 256)
        float s = 0.f, q = 0.f;
        #pragma unroll
        for (int nt = 0; nt < NT; ++nt)
            #pragma unroll
            for (int i = 0; i < 4; ++i) { float v = acc[nt][i]; s += v; q += v * v; }
        s += __shfl_xor(s, 16); q += __shfl_xor(q, 16);
        s += __shfl_xor(s, 32); q += __shfl_xor(q, 32);
        float mean = s * (1.0f / 256.0f);
        float rstd = rsqrtf(q * (1.0f / 256.0f) - mean * mean + EPSV);
        #pragma unroll
        for (int nt = 0; nt < NT; ++nt) {
            float4 gg = *(const float4*)(g1 + nt * 16 + c4);
            float4 bb = *(const float4*)(b1 + nt * 16 + c4);
            bf16x4 st;
            st[0] = (bf16)fmaxf((acc[nt][0] - mean) * rstd * gg.x + bb.x, 0.f);
            st[1] = (bf16)fmaxf((acc[nt][1] - mean) * rstd * gg.y + bb.y, 0.f);
            st[2] = (bf16)fmaxf((acc[nt][2] - mean) * rstd * gg.z + bb.z, 0.f);
            st[3] = (bf16)fmaxf((acc[nt][3] - mean) * rstd * gg.w + bb.w, 0.f);
            *(bf16x4*)(O0 + row * 256 + nt * 16 + c4) = st;
        }
    } else if (EPI == 2) {                // residual in-place
        #pragma unroll
        for (int nt = 0; nt < NT; ++nt) {
            bf16* p = O0 + row * 256 + colblk + nt * 16 + c4;
            bf16x4 hv = *(const bf16x4*)p;
            bf16x4 st;
            #pragma unroll
            for (int i = 0; i < 4; ++i) st[i] = (bf16)(acc[nt][i] + (float)hv[i]);
            *(bf16x4*)p = st;
        }
    } else if (EPI == 3) {                // in_proj: x-half plain, z-half silu
        bf16* dst;
        int cb;
        const int dosilu = (colblk >= 256);
        if (dosilu) { dst = O1; cb = colblk - 256; }
        else        { dst = O0; cb = colblk; }
        #pragma unroll
        for (int nt = 0; nt < NT; ++nt) {
            bf16x4 st;
            #pragma unroll
            for (int i = 0; i < 4; ++i) {
                float v = acc[nt][i];
                if (dosilu) v = silu_f(v);
                st[i] = (bf16)v;
            }
            *(bf16x4*)(dst + row * 256 + cb + nt * 16 + c4) = st;
        }
    } else {                              // EPI 4: +h, LN, fp32 out (NCOLS == 256)
        #pragma unroll
        for (int nt = 0; nt < NT; ++nt) {
            bf16x4 hv = *(const bf16x4*)(O0 + row * 256 + nt * 16 + c4);
            #pragma unroll
            for (int i = 0; i < 4; ++i) acc[nt][i] += (float)hv[i];
        }
        float s = 0.f, q = 0.f;
        #pragma unroll
        for (int nt = 0; nt < NT; ++nt)
            #pragma unroll
            for (int i = 0; i < 4; ++i) { float v = acc[nt][i]; s += v; q += v * v; }
        s += __shfl_xor(s, 16); q += __shfl_xor(q, 16);
        s += __shfl_xor(s, 32); q += __shfl_xor(q, 32);
        float mean = s * (1.0f / 256.0f);
        float rstd = rsqrtf(q * (1.0f / 256.0f) - mean * mean + EPSV);
        #pragma unroll
        for (int nt = 0; nt < NT; ++nt) {
            float4 gg = *(const float4*)(g1 + nt * 16 + c4);
            float4 bb = *(const float4*)(b1 + nt * 16 + c4);
            float4 o;
            o.x = (acc[nt][0] - mean) * rstd * gg.x + bb.x;
            o.y = (acc[nt][1] - mean) * rstd * gg.y + bb.y;
            o.z = (acc[nt][2] - mean) * rstd * gg.z + bb.z;
            o.w = (acc[nt][3] - mean) * rstd * gg.w + bb.w;
            *(float4*)(Of + row * 256 + nt * 16 + c4) = o;
        }
    }
}

// ---------------------------------------------------------------------------
// pass 1: conv(K=4)+SiLU+local EMA inside a 64-step chunk; emit chunk-final only.
__global__ void pass1_k(const bf16* __restrict__ xc,
                        const float* __restrict__ cw, const float* __restrict__ cb,
                        float* __restrict__ cfin)
{
    const int d0 = threadIdx.x * 2;
    const int c = blockIdx.x, b = blockIdx.y;
    const int t0 = c * CH;
    const float w00=cw[d0*4+0], w01=cw[d0*4+1], w02=cw[d0*4+2], w03=cw[d0*4+3];
    const float w10=cw[d0*4+4], w11=cw[d0*4+5], w12=cw[d0*4+6], w13=cw[d0*4+7];
    const float bb0 = cb[d0], bb1 = cb[d0+1];
    const float a0 = decay_of(d0), a1 = decay_of(d0+1);
    const size_t base = (size_t)b * TT * 256 + d0;
    float x0m1=0,x0m2=0,x0m3=0, x1m1=0,x1m2=0,x1m3=0;
    if (t0 >= 1) { bf16x2 p = *(const bf16x2*)(xc + base + (size_t)(t0-1)*256); x0m1=(float)p[0]; x1m1=(float)p[1]; }
    if (t0 >= 2) { bf16x2 p = *(const bf16x2*)(xc + base + (size_t)(t0-2)*256); x0m2=(float)p[0]; x1m2=(float)p[1]; }
    if (t0 >= 3) { bf16x2 p = *(const bf16x2*)(xc + base + (size_t)(t0-3)*256); x0m3=(float)p[0]; x1m3=(float)p[1]; }
    float h0 = 0.f, h1 = 0.f;
    for (int t = t0; t < t0 + CH; ++t) {
        bf16x2 p = *(const bf16x2*)(xc + base + (size_t)t * 256);
        float xa = (float)p[0], xb = (float)p[1];
        float v0 = w03*xa + w02*x0m1 + w01*x0m2 + w00*x0m3 + bb0;
        float v1 = w13*xb + w12*x1m1 + w11*x1m2 + w10*x1m3 + bb1;
        h0 = a0*h0 + (1.f-a0)*silu_f(v0);
        h1 = a1*h1 + (1.f-a1)*silu_f(v1);
        x0m3=x0m2; x0m2=x0m1; x0m1=xa;
        x1m3=x1m2; x1m2=x1m1; x1m1=xb;
    }
    *(float2*)(cfin + ((size_t)b*NC + c)*256 + d0) = make_float2(h0, h1);
}

// pass 2: per-(b,d) carry recurrence over the 64 chunk finals.
__global__ void scan2_k(const float* __restrict__ cfin, float* __restrict__ cin)
{
    const int d = threadIdx.x, b = blockIdx.x;
    float a = decay_of(d);
    float aC = a;
    #pragma unroll
    for (int j = 0; j < 6; ++j) aC *= aC;   // a^64
    float H = 0.f;
    for (int c = 0; c < NC; ++c) {
        size_t o = ((size_t)b * NC + c) * 256 + d;
        cin[o] = H;
        H = aC * H + cfin[o];
    }
}

// pass 3: recompute conv+SiLU+EMA with exact carry-in; u = hi * sz; u aliases sz.
__global__ void pass3_k(const bf16* __restrict__ xc, const float* __restrict__ cin,
                        const float* __restrict__ cw, const float* __restrict__ cb,
                        bf16* __restrict__ szu)
{
    const int d0 = threadIdx.x * 2;
    const int c = blockIdx.x, b = blockIdx.y;
    const int t0 = c * CH;
    const float w00=cw[d0*4+0], w01=cw[d0*4+1], w02=cw[d0*4+2], w03=cw[d0*4+3];
    const float w10=cw[d0*4+4], w11=cw[d0*4+5], w12=cw[d0*4+6], w13=cw[d0*4+7];
    const float bb0 = cb[d0], bb1 = cb[d0+1];
    const float a0 = decay_of(d0), a1 = decay_of(d0+1);
    const size_t base = (size_t)b * TT * 256 + d0;
    float2 Hc = *(const float2*)(cin + ((size_t)b*NC + c)*256 + d0);
    float h0 = Hc.x, h1 = Hc.y;
    float x0m1=0,x0m2=0,x0m3=0, x1m1=0,x1m2=0,x1m3=0;
    if (t0 >= 1) { bf16x2 p = *(const bf16x2*)(xc + base + (size_t)(t0-1)*256); x0m1=(float)p[0]; x1m1=(float)p[1]; }
    if (t0 >= 2) { bf16x2 p = *(const bf16x2*)(xc + base + (size_t)(t0-2)*256); x0m2=(float)p[0]; x1m2=(float)p[1]; }
    if (t0 >= 3) { bf16x2 p = *(const bf16x2*)(xc + base + (size_t)(t0-3)*256); x0m3=(float)p[0]; x1m3=(float)p[1]; }
    for (int t = t0; t < t0 + CH; ++t) {
        bf16x2 p = *(const bf16x2*)(xc + base + (size_t)t * 256);
        float xa = (float)p[0], xb = (float)p[1];
        float v0 = w03*xa + w02*x0m1 + w01*x0m2 + w00*x0m3 + bb0;
        float v1 = w13*xb + w12*x1m1 + w11*x1m2 + w10*x1m3 + bb1;
        h0 = a0*h0 + (1.f-a0)*silu_f(v0);
        h1 = a1*h1 + (1.f-a1)*silu_f(v1);
        x0m3=x0m2; x0m2=x0m1; x0m1=xa;
        x1m3=x1m2; x1m2=x1m1; x1m1=xb;
        bf16* up = szu + base + (size_t)t * 256;
        bf16x2 sp = *(const bf16x2*)up;
        bf16x2 st;
        st[0] = (bf16)(h0 * (float)sp[0]);
        st[1] = (bf16)(h1 * (float)sp[1]);
        *(bf16x2*)up = st;
    }
}

// ---------------------------------------------------------------------------
extern "C" void kernel_launch(void* const* d_in, const int* in_sizes, int n_in,
                              void* d_out, int out_size, void* d_ws, size_t ws_size,
                              hipStream_t stream)
{
    (void)in_sizes; (void)n_in; (void)out_size;
    const float* x        = (const float*)d_in[0];
    const float* enc_w    = (const float*)d_in[1];
    const float* enc_b    = (const float*)d_in[2];
    const float* enc_ln_g = (const float*)d_in[3];
    const float* enc_ln_b = (const float*)d_in[4];
    const float* in_proj_w  = (const float*)d_in[5];
    const float* in_proj_b  = (const float*)d_in[6];
    const float* conv_w     = (const float*)d_in[7];
    const float* conv_b     = (const float*)d_in[8];
    const float* out_proj_w = (const float*)d_in[9];
    const float* out_proj_b = (const float*)d_in[10];
    const float* lnf_g      = (const float*)d_in[11];
    const float* lnf_b      = (const float*)d_in[12];

    // workspace: h (64MiB) | sz/u (64MiB) | wenc 128K | winp 512K | woutp 256K | cfin 2M | cin 2M
    if (ws_size < 139329536u) return;
    char* ws = (char*)d_ws;
    bf16*  h     = (bf16*)(ws);
    bf16*  szu   = (bf16*)(ws + 67108864);
    bf16*  wenc  = (bf16*)(ws + 134217728);
    bf16*  winp  = (bf16*)(ws + 134217728 + 131072);
    bf16*  woutp = (bf16*)(ws + 134217728 + 131072 + 524288);
    float* cfin  = (float*)(ws + 134217728 + 917504);
    float* cin   = (float*)(ws + 134217728 + 917504 + 2097152);
    bf16*  xc    = (bf16*)d_out;   // first 64 MiB of d_out as bf16 scratch

    cvtw_k<<<dim3(448), dim3(1024), 0, stream>>>(enc_w, in_proj_w, out_proj_w,
                                                 wenc, winp, woutp);

    dim3 gblk(512);
    // encoder: h = relu(LN(x @ enc_w^T + enc_b))   [fat 256-col, LN epilogue]
    gemm_k<1, 1, 256, 2><<<dim3(1024, 1), gblk, 0, stream>>>(x, wenc, enc_b,
                                                    enc_ln_g, enc_ln_b, h, nullptr, nullptr);
    for (int l = 0; l < LL; ++l) {
        // xc = h @ Wx^T + bx ; sz = silu(h @ Wz^T + bz)   [slim 128-col, 4 y-blocks]
        gemm_k<0, 3, 128, 4><<<dim3(1024, 4), gblk, 0, stream>>>(h, winp + (size_t)l * 512 * 256,
                                                        in_proj_b + l * 512, nullptr, nullptr,
                                                        xc, szu, nullptr);
        pass1_k<<<dim3(NC, BB), dim3(128), 0, stream>>>(xc, conv_w + l * DD * 4,
                                                        conv_b + l * DD, cfin);
        scan2_k<<<dim3(BB), dim3(256), 0, stream>>>(cfin, cin);
        pass3_k<<<dim3(NC, BB), dim3(128), 0, stream>>>(xc, cin, conv_w + l * DD * 4,
                                                        conv_b + l * DD, szu);
        if (l == 0) {
            // h += u @ out_proj_w[0]^T + b   [slim 128-col, 2 y-blocks]
            gemm_k<0, 2, 128, 4><<<dim3(1024, 2), gblk, 0, stream>>>(szu, woutp,
                                                            out_proj_b, nullptr, nullptr,
                                                            h, nullptr, nullptr);
        } else {
            // out = LN(h + u @ out_proj_w[1]^T + b) -> fp32 d_out   [fat 256-col]
            gemm_k<0, 4, 256, 2><<<dim3(1024, 1), gblk, 0, stream>>>(szu, woutp + (size_t)256 * 256,
                                                            out_proj_b + 256, lnf_g, lnf_b,
                                                            h, nullptr, (float*)d_out);
        }
    }
}